// Round 1
// baseline (2159.790 us; speedup 1.0000x reference)
//
#include <hip/hip_runtime.h>
#include <hip/hip_bf16.h>

constexpr int D_  = 4096;
constexpr int L_  = 24;
constexpr int T_  = 512;
constexpr int N_  = 2048;
constexpr int H_  = 8;
constexpr int HD_ = 512;
constexpr float SCALE_ = 0.04419417382415922f; // 1/sqrt(512)

typedef __attribute__((ext_vector_type(8))) short short8;
typedef __attribute__((ext_vector_type(4))) float f32x4;

__device__ __forceinline__ unsigned short f2b(float f){
  union{float f; unsigned u;} v; v.f=f;
  return (unsigned short)((v.u + 0x7fffu + ((v.u>>16)&1u))>>16);
}
__device__ __forceinline__ float b2f(unsigned short h){
  union{unsigned u; float f;} v; v.u=((unsigned)h)<<16; return v.f;
}

// ---------------- column-mean partials: src [l][R][D] -> part[(l*S+s)*D + d] ---------------
__global__ void colsum_part_l(const float* __restrict__ src, float* __restrict__ part,
                              int R, int S){
  const int d = blockIdx.x*256 + threadIdx.x;
  const int s = blockIdx.y, l = blockIdx.z;
  const int rows = R / S;
  const float* p = src + (size_t)l*R*D_ + (size_t)s*rows*D_ + d;
  float acc = 0.f;
  for(int r=0;r<rows;++r) acc += p[(size_t)r*D_];
  part[((size_t)l*S + s)*D_ + d] = acc;
}

// MODE 0: mean (a*inv); 1: tanh(a+bias); 2: a+bias
template<int MODE>
__global__ void reduce_LD(const float* __restrict__ part, const float* __restrict__ bias,
                          float* __restrict__ out, int S, float inv){
  const int i = blockIdx.x*256 + threadIdx.x;
  const int l = i >> 12, j = i & (D_-1);
  float a = 0.f;
  for(int s=0;s<S;++s) a += part[((size_t)l*S + s)*D_ + j];
  if(MODE==0)      out[i] = a * inv;
  else if(MODE==1) out[i] = tanhf(a + bias[j]);
  else             out[i] = a + bias[j];
}

// ------------- small-M (24-row) GEMM partials over split-K ----------------
// WHICH=0: X=[y|e], W=Wc (K=8192).  WHICH=1: X=[y|e|tg], W=Wz rows {0:D, 2D:4D} (K=12288)
template<int WHICH>
__global__ void smallm_part(const float* __restrict__ W, const float* __restrict__ y,
                            const float* __restrict__ e, const float* __restrict__ tg,
                            float* __restrict__ part, int klen){
  const int j = blockIdx.x*256 + threadIdx.x;
  const int s = blockIdx.y, S = gridDim.y;
  const int k0 = s * klen;
  float acc[L_];
#pragma unroll
  for(int l=0;l<L_;++l) acc[l]=0.f;
  __shared__ float xs[L_][64];
  for(int kc=0; kc<klen; kc+=64){
    __syncthreads();
    for(int i=threadIdx.x; i<L_*64; i+=256){
      const int l=i>>6, kk=i&63, k=k0+kc+kk;
      float xv;
      if(WHICH==0) xv = (k<D_)? y[(size_t)l*D_+k] : e[(size_t)l*D_ + (k-D_)];
      else xv = (k<D_)? y[(size_t)l*D_+k]
              : ((k<2*D_)? e[(size_t)l*D_ + (k-D_)] : tg[k-2*D_]);
      xs[l][kk]=xv;
    }
    __syncthreads();
    for(int kk=0;kk<64;++kk){
      const int k=k0+kc+kk;
      const int wrow = (WHICH==0)? k : ((k<D_)? k : k+D_);
      const float wv = W[(size_t)wrow*D_ + j];
#pragma unroll
      for(int l=0;l<L_;++l) acc[l] += xs[l][kk]*wv;
    }
  }
  for(int l=0;l<L_;++l) part[((size_t)l*S + s)*D_ + j] = acc[l];
}

// ------------- recurrence: split-K matvec with Wz_c (rows D..2D-1), then gate -------------
__global__ void matvec_part(const float* __restrict__ Wz, const float* __restrict__ c,
                            float* __restrict__ zpart){
  const int j = blockIdx.x*256 + threadIdx.x;
  const int s = blockIdx.y;
  const int k0 = s*128;
  __shared__ float cs[128];
  if(threadIdx.x<128) cs[threadIdx.x] = c[k0+threadIdx.x];
  __syncthreads();
  float acc=0.f;
  const float* Wp = Wz + ((size_t)(D_ + k0))*D_ + j;
  for(int kk=0; kk<128; ++kk) acc += cs[kk]*Wp[(size_t)kk*D_];
  zpart[(size_t)s*D_ + j]=acc;
}

__global__ void gate_step(const float* __restrict__ zpart, const float* __restrict__ aall,
                          const float* __restrict__ ct, float* __restrict__ c, int l){
  const int j = blockIdx.x*256+threadIdx.x;
  float zl = aall[(size_t)l*D_ + j];
  for(int s=0;s<32;++s) zl += zpart[(size_t)s*D_ + j];
  const float z = 1.f/(1.f + expf(-zl*(1.f/3.f)));
  const float cp = c[j];
  c[j] = cp + z*(ct[(size_t)l*D_ + j] - cp);
}

__global__ void zero_vec(float* p){ p[blockIdx.x*256+threadIdx.x]=0.f; }

// ---------------- row LayerNorm (D=4096), 256 thr/row ----------------
template<bool ADDC, bool AFF, bool OBF>
__global__ void row_ln(const float* __restrict__ x, const float* __restrict__ cvec,
                       const float* __restrict__ w, const float* __restrict__ b,
                       float* __restrict__ of, unsigned short* __restrict__ ob){
  __shared__ float sm[256];
  const int row = blockIdx.x, t = threadIdx.x;
  const float* xr = x + (size_t)row*D_;
  float v[16];
  float s=0.f;
#pragma unroll
  for(int i=0;i<16;++i){
    const int d = i*256 + t;
    float val = xr[d];
    if(ADDC) val += cvec[d];
    v[i]=val; s+=val;
  }
  sm[t]=s; __syncthreads();
  for(int o=128;o>0;o>>=1){ if(t<o) sm[t]+=sm[t+o]; __syncthreads(); }
  const float mean = sm[0]*(1.f/D_); __syncthreads();
  float q=0.f;
#pragma unroll
  for(int i=0;i<16;++i){ const float dd=v[i]-mean; q+=dd*dd; }
  sm[t]=q; __syncthreads();
  for(int o=128;o>0;o>>=1){ if(t<o) sm[t]+=sm[t+o]; __syncthreads(); }
  const float rstd = rsqrtf(sm[0]*(1.f/D_) + 1e-5f);
#pragma unroll
  for(int i=0;i<16;++i){
    const int d = i*256+t;
    float yv=(v[i]-mean)*rstd;
    if(AFF) yv = yv*w[d] + b[d];
    if(OBF) ob[(size_t)row*D_ + d] = f2b(yv);
    else    of[(size_t)row*D_ + d] = yv;
  }
}

// ---------------- row softmax in-place on bf16 [rows][N_] ----------------
__global__ void softmax_rows(unsigned short* __restrict__ wb){
  __shared__ float sm[256];
  const size_t base = (size_t)blockIdx.x * N_;
  const int t = threadIdx.x;
  float v[8];
  float mx = -3.4e38f;
#pragma unroll
  for(int i=0;i<8;++i){ v[i]=b2f(wb[base + i*256 + t]); mx=fmaxf(mx,v[i]); }
  sm[t]=mx; __syncthreads();
  for(int o=128;o>0;o>>=1){ if(t<o) sm[t]=fmaxf(sm[t],sm[t+o]); __syncthreads(); }
  mx=sm[0]; __syncthreads();
  float s=0.f;
#pragma unroll
  for(int i=0;i<8;++i){ v[i]=expf(v[i]-mx); s+=v[i]; }
  sm[t]=s; __syncthreads();
  for(int o=128;o>0;o>>=1){ if(t<o) sm[t]+=sm[t+o]; __syncthreads(); }
  const float inv = 1.f/sm[0];
#pragma unroll
  for(int i=0;i<8;++i) wb[base + i*256 + t] = f2b(v[i]*inv);
}

// ---------------- generic MFMA GEMM, 128x128x32 tiles, 4 waves ----------------
enum { EPI_F32_BIAS=0, EPI_BF16_GELU=1, EPI_SPATIAL=2, EPI_BF16_SCALE=3, EPI_BF16=4 };
constexpr int BM=128, BN=128, BK=32, LDT=56; // LDT*2=112B row stride: 16B-aligned, low conflicts

__device__ __forceinline__ void cvt16(const float* p, unsigned short* o){
#pragma unroll
  for(int q=0;q<4;++q){
    float4 v = *(const float4*)(p+4*q);
    o[4*q+0]=f2b(v.x); o[4*q+1]=f2b(v.y); o[4*q+2]=f2b(v.z); o[4*q+3]=f2b(v.w);
  }
}
__device__ __forceinline__ void cvt16(const unsigned short* p, unsigned short* o){
#pragma unroll
  for(int q=0;q<2;++q) *(uint4*)(o+8*q) = *(const uint4*)(p+8*q);
}
__device__ __forceinline__ void ld2f(const float* p, float& a, float& b){
  float2 v=*(const float2*)p; a=v.x; b=v.y;
}
__device__ __forceinline__ void ld2f(const unsigned short* p, float& a, float& b){
  unsigned v=*(const unsigned*)p; a=b2f((unsigned short)(v&0xffffu)); b=b2f((unsigned short)(v>>16));
}

template<typename TA, typename TB, bool BTRANS, int EPI>
__global__ __launch_bounds__(256,2) void gemm_k(
  const TA* __restrict__ A, const TB* __restrict__ B, const float* __restrict__ bias,
  float* __restrict__ Cf, unsigned short* __restrict__ Cb,
  int M, int Nc, int K, int lda, int ldb, int ldc,
  long long aZ, long long bZ, long long cZ,
  const float* __restrict__ pre, const float* __restrict__ alphap, float scale)
{
  __shared__ unsigned short As[BM*LDT];
  __shared__ unsigned short Bs[BN*LDT];
  const int t = threadIdx.x;
  const int m0 = blockIdx.x*BM, n0 = blockIdx.y*BN;
  const int hz = blockIdx.z;
  A += (size_t)hz*aZ; B += (size_t)hz*bZ;
  const size_t coff = (size_t)hz*cZ;

  f32x4 acc[4][4];
#pragma unroll
  for(int i=0;i<4;++i)
#pragma unroll
    for(int j=0;j<4;++j) acc[i][j]=(f32x4){0.f,0.f,0.f,0.f};

  const int lane = t&63, wid=t>>6;
  const int wm=(wid>>1)*64, wn=(wid&1)*64;
  const int lrow=lane&15, lk=(lane>>4)*8;

  for(int k0=0;k0<K;k0+=BK){
    __syncthreads();
    { // A stage: [BM][BK], row-major in K
      const int row=t>>1, kq=(t&1)*16;
      unsigned short tmp[16] __attribute__((aligned(16)));
      cvt16(A + (size_t)(m0+row)*lda + k0 + kq, tmp);
      *(uint4*)&As[row*LDT+kq]   = *(const uint4*)&tmp[0];
      *(uint4*)&As[row*LDT+kq+8] = *(const uint4*)&tmp[8];
    }
    if(BTRANS){ // B given as BT[N][K] row-major
      const int row=t>>1, kq=(t&1)*16;
      unsigned short tmp[16] __attribute__((aligned(16)));
      cvt16(B + (size_t)(n0+row)*ldb + k0 + kq, tmp);
      *(uint4*)&Bs[row*LDT+kq]   = *(const uint4*)&tmp[0];
      *(uint4*)&Bs[row*LDT+kq+8] = *(const uint4*)&tmp[8];
    } else {    // B given as [K][N]: transpose in staging (coalesced reads, b128 writes)
      const int ln_=t&63, grp=t>>6;
      const TB* bp = B + (size_t)(k0+grp*8)*ldb + n0 + 2*ln_;
      unsigned short c0[8] __attribute__((aligned(16)));
      unsigned short c1[8] __attribute__((aligned(16)));
#pragma unroll
      for(int q=0;q<8;++q){
        float x0,x1; ld2f(bp + (size_t)q*ldb, x0,x1);
        c0[q]=f2b(x0); c1[q]=f2b(x1);
      }
      *(uint4*)&Bs[(2*ln_+0)*LDT + grp*8] = *(const uint4*)&c0[0];
      *(uint4*)&Bs[(2*ln_+1)*LDT + grp*8] = *(const uint4*)&c1[0];
    }
    __syncthreads();
    short8 af[4], bfr[4];
#pragma unroll
    for(int i=0;i<4;++i) af[i]  = *(const short8*)&As[(wm+i*16+lrow)*LDT + lk];
#pragma unroll
    for(int j=0;j<4;++j) bfr[j] = *(const short8*)&Bs[(wn+j*16+lrow)*LDT + lk];
#pragma unroll
    for(int i=0;i<4;++i)
#pragma unroll
      for(int j=0;j<4;++j)
        acc[i][j] = __builtin_amdgcn_mfma_f32_16x16x32_bf16(af[i], bfr[j], acc[i][j], 0,0,0);
  }

  float ta=0.f;
  if(EPI==EPI_SPATIAL) ta = tanhf(alphap[0]);
#pragma unroll
  for(int i=0;i<4;++i)
#pragma unroll
    for(int j=0;j<4;++j){
      const int col = n0 + wn + j*16 + lrow;
      const int rb  = m0 + wm + i*16 + (lane>>4)*4;
#pragma unroll
      for(int r=0;r<4;++r){
        const int row = rb + r;
        const float v = acc[i][j][r];
        const size_t idx = coff + (size_t)row*ldc + col;
        if(EPI==EPI_F32_BIAS){ Cf[idx] = v + bias[col]; }
        else if(EPI==EPI_BF16_GELU){
          const float x=v+bias[col];
          Cb[idx]=f2b(0.5f*x*(1.f+erff(x*0.70710678118f)));
        }
        else if(EPI==EPI_SPATIAL){
          const float x=tanhf(v+bias[col]);
          Cf[idx]= pre[(size_t)row*ldc+col] + ta*x;
        }
        else if(EPI==EPI_BF16_SCALE){ Cb[idx]=f2b(v*scale); }
        else { Cb[idx]=f2b(v); }
      }
    }
}

// ---------------- workspace layout (bytes) ----------------
constexpr size_t OFF_TG   = 0;
constexpr size_t OFF_GM   = OFF_TG + (size_t)D_*4;
constexpr size_t OFF_C    = OFF_GM + (size_t)D_*4;
constexpr size_t OFF_Y    = OFF_C  + (size_t)D_*4;
constexpr size_t OFF_CT   = OFF_Y  + (size_t)L_*D_*4;
constexpr size_t OFF_AA   = OFF_CT + (size_t)L_*D_*4;
constexpr size_t OFF_ZP   = OFF_AA + (size_t)L_*D_*4;
constexpr size_t OFF_PART = OFF_ZP + (size_t)32*D_*4;
constexpr size_t OFF_QPRE = OFF_PART + (size_t)24*L_*D_*4;   // also opre
constexpr size_t OFF_REFR = OFF_QPRE + (size_t)T_*D_*4;
constexpr size_t OFF_HB   = OFF_REFR + (size_t)N_*D_*4;      // bf16; kpre (fp32) reuses HB+G1
constexpr size_t OFF_G1   = OFF_HB + (size_t)N_*D_*2;
constexpr size_t OFF_KPRE = OFF_HB;
constexpr size_t OFF_QB   = OFF_G1 + (size_t)N_*D_*2;
constexpr size_t OFF_KB   = OFF_QB + (size_t)T_*D_*2;
constexpr size_t OFF_VB   = OFF_KB + (size_t)N_*D_*2;
constexpr size_t OFF_WB   = OFF_VB + (size_t)N_*D_*2;        // scores/weights bf16 [H][T][N]
constexpr size_t OFF_ATTN = OFF_WB + (size_t)H_*T_*N_*2;

extern "C" void kernel_launch(void* const* d_in, const int* in_sizes, int n_in,
                              void* d_out, int out_size, void* d_ws, size_t ws_size,
                              hipStream_t stream){
  (void)in_sizes; (void)n_in; (void)out_size; (void)ws_size;
  const float* text  = (const float*)d_in[0];
  const float* layers= (const float*)d_in[1];
  const float* le    = (const float*)d_in[2];
  const float* Wc    = (const float*)d_in[3];
  const float* Wcb   = (const float*)d_in[4];
  const float* Wz    = (const float*)d_in[5];
  const float* Wzb   = (const float*)d_in[6];
  const float* d1w   = (const float*)d_in[7];
  const float* d1b   = (const float*)d_in[8];
  const float* d2w   = (const float*)d_in[9];
  const float* d2b   = (const float*)d_in[10];
  const float* alpha = (const float*)d_in[11];
  const float* Wqw=(const float*)d_in[12]; const float* Wqb=(const float*)d_in[13];
  const float* Wkw=(const float*)d_in[14]; const float* Wkb=(const float*)d_in[15];
  const float* Wow=(const float*)d_in[16]; const float* Wob=(const float*)d_in[17];
  const float* qnw=(const float*)d_in[18]; const float* qnb=(const float*)d_in[19];
  const float* knw=(const float*)d_in[20]; const float* knb=(const float*)d_in[21];
  const float* vnw=(const float*)d_in[22]; const float* vnb=(const float*)d_in[23];
  const float* onw=(const float*)d_in[24]; const float* onb=(const float*)d_in[25];
  float* out = (float*)d_out;

  char* w = (char*)d_ws;
  float* tg    = (float*)(w + OFF_TG);
  float* gm    = (float*)(w + OFF_GM);
  float* cvec  = (float*)(w + OFF_C);
  float* y     = (float*)(w + OFF_Y);
  float* ct    = (float*)(w + OFF_CT);
  float* aall  = (float*)(w + OFF_AA);
  float* zpart = (float*)(w + OFF_ZP);
  float* part  = (float*)(w + OFF_PART);
  float* qpre  = (float*)(w + OFF_QPRE);
  float* opre  = qpre;
  float* refr  = (float*)(w + OFF_REFR);
  float* kpre  = (float*)(w + OFF_KPRE);
  unsigned short* hb    = (unsigned short*)(w + OFF_HB);
  unsigned short* g1    = (unsigned short*)(w + OFF_G1);
  unsigned short* qb    = (unsigned short*)(w + OFF_QB);
  unsigned short* kb    = (unsigned short*)(w + OFF_KB);
  unsigned short* vb    = (unsigned short*)(w + OFF_VB);
  unsigned short* wb    = (unsigned short*)(w + OFF_WB);
  unsigned short* attnb = (unsigned short*)(w + OFF_ATTN);

  const dim3 b256(256);
  const float* pre23 = layers + (size_t)(L_-2)*N_*D_;

  // text_global = LN(mean(text, axis=0))
  colsum_part_l<<<dim3(16,8,1),b256,0,stream>>>(text, part, T_, 8);
  reduce_LD<0><<<dim3(16),b256,0,stream>>>(part, nullptr, gm, 8, 1.f/T_);
  row_ln<false,false,false><<<dim3(1),b256,0,stream>>>(gm, nullptr,nullptr,nullptr, tg, nullptr);

  // y[l] = mean(layer_features[l], axis=0)
  colsum_part_l<<<dim3(16,8,24),b256,0,stream>>>(layers, part, N_, 8);
  reduce_LD<0><<<dim3(384),b256,0,stream>>>(part, nullptr, y, 8, 1.f/N_);

  // c_tilde batch and z-logit static part
  smallm_part<0><<<dim3(16,16),b256,0,stream>>>(Wc, y, le, tg, part, 512);
  reduce_LD<1><<<dim3(384),b256,0,stream>>>(part, Wcb, ct, 16, 0.f);
  smallm_part<1><<<dim3(16,24),b256,0,stream>>>(Wz, y, le, tg, part, 512);
  reduce_LD<2><<<dim3(384),b256,0,stream>>>(part, Wzb, aall, 24, 0.f);

  // recurrence, steps 0..22 -> c = contexts[-2]
  zero_vec<<<dim3(16),b256,0,stream>>>(cvec);
  for(int l=0;l<L_-1;++l){
    matvec_part<<<dim3(16,32),b256,0,stream>>>(Wz, cvec, zpart);
    gate_step<<<dim3(16),b256,0,stream>>>(zpart, aall, ct, cvec, l);
  }

  // SpatialGate
  row_ln<true,false,true><<<dim3(N_),b256,0,stream>>>(pre23, cvec, nullptr,nullptr, nullptr, hb);
  gemm_k<unsigned short,float,false,EPI_BF16_GELU><<<dim3(16,32,1),b256,0,stream>>>(
      hb, d1w, d1b, nullptr, g1, N_, D_, D_, D_, D_, D_, 0,0,0, nullptr,nullptr,0.f);
  gemm_k<unsigned short,float,false,EPI_SPATIAL><<<dim3(16,32,1),b256,0,stream>>>(
      g1, d2w, d2b, refr, nullptr, N_, D_, D_, D_, D_, D_, 0,0,0, pre23, alpha, 0.f);

  // Q / K / V
  gemm_k<float,float,false,EPI_F32_BIAS><<<dim3(4,32,1),b256,0,stream>>>(
      text, Wqw, Wqb, qpre, nullptr, T_, D_, D_, D_, D_, D_, 0,0,0, nullptr,nullptr,0.f);
  row_ln<false,true,true><<<dim3(T_),b256,0,stream>>>(qpre, nullptr, qnw, qnb, nullptr, qb);
  row_ln<false,true,true><<<dim3(N_),b256,0,stream>>>(refr, nullptr, vnw, vnb, nullptr, vb);
  gemm_k<float,float,false,EPI_F32_BIAS><<<dim3(16,32,1),b256,0,stream>>>(
      refr, Wkw, Wkb, kpre, nullptr, N_, D_, D_, D_, D_, D_, 0,0,0, nullptr,nullptr,0.f);
  row_ln<false,true,true><<<dim3(N_),b256,0,stream>>>(kpre, nullptr, knw, knb, nullptr, kb);

  // attention
  gemm_k<unsigned short,unsigned short,true,EPI_BF16_SCALE><<<dim3(4,16,8),b256,0,stream>>>(
      qb, kb, nullptr, nullptr, wb, T_, N_, HD_, D_, D_, N_,
      (long long)HD_, (long long)HD_, (long long)T_*N_, nullptr,nullptr, SCALE_);
  softmax_rows<<<dim3(H_*T_),b256,0,stream>>>(wb);
  gemm_k<unsigned short,unsigned short,false,EPI_BF16><<<dim3(4,4,8),b256,0,stream>>>(
      wb, vb, nullptr, nullptr, attnb, T_, HD_, N_, N_, D_, D_,
      (long long)T_*N_, (long long)HD_, (long long)HD_, nullptr,nullptr,0.f);

  // output projection + final LN
  gemm_k<unsigned short,float,false,EPI_F32_BIAS><<<dim3(4,32,1),b256,0,stream>>>(
      attnb, Wow, Wob, opre, nullptr, T_, D_, D_, D_, D_, D_, 0,0,0, nullptr,nullptr,0.f);
  row_ln<false,true,false><<<dim3(T_),b256,0,stream>>>(opre, nullptr, onw, onb, out, nullptr);
}

// Round 2
// 1786.967 us; speedup vs baseline: 1.2086x; 1.2086x over previous
//
#include <hip/hip_runtime.h>
#include <hip/hip_bf16.h>

constexpr int D_  = 4096;
constexpr int L_  = 24;
constexpr int T_  = 512;
constexpr int N_  = 2048;
constexpr int H_  = 8;
constexpr int HD_ = 512;
constexpr float SCALE_ = 0.04419417382415922f; // 1/sqrt(512)

typedef __attribute__((ext_vector_type(8))) short short8;
typedef __attribute__((ext_vector_type(4))) float f32x4;

__device__ __forceinline__ unsigned short f2b(float f){
  union{float f; unsigned u;} v; v.f=f;
  return (unsigned short)((v.u + 0x7fffu + ((v.u>>16)&1u))>>16);
}
__device__ __forceinline__ float b2f(unsigned short h){
  union{unsigned u; float f;} v; v.u=((unsigned)h)<<16; return v.f;
}

__device__ __forceinline__ void gload_lds16(const unsigned short* g, unsigned short* l){
  __builtin_amdgcn_global_load_lds((const __attribute__((address_space(1))) unsigned int*)g,
                                   (__attribute__((address_space(3))) unsigned int*)l, 16, 0, 0);
}

// ---------------- prepass: f32 [K][N] -> bf16 [N][K] transpose ----------------
__global__ void transpose_f32_bf16T(const float* __restrict__ in, unsigned short* __restrict__ out,
                                    int K, int N){
  __shared__ float tile[64][65];
  const int t = threadIdx.x;
  const int k0 = blockIdx.x*64, n0 = blockIdx.y*64;
  const int tr = t>>6, tc = t&63;
#pragma unroll
  for(int i=0;i<16;++i) tile[i*4+tr][tc] = in[(size_t)(k0+i*4+tr)*N + n0+tc];
  __syncthreads();
#pragma unroll
  for(int i=0;i<16;++i) out[(size_t)(n0+i*4+tr)*K + k0+tc] = f2b(tile[tc][i*4+tr]);
}

// ---------------- prepass: elementwise f32 -> bf16 (8 elems/thread) ----------------
__global__ void cvt_f32_bf16(const float* __restrict__ in, unsigned short* __restrict__ out){
  const int i = blockIdx.x*256 + threadIdx.x;
  const float4 a = ((const float4*)in)[2*i], b = ((const float4*)in)[2*i+1];
  unsigned short o[8] __attribute__((aligned(16)));
  o[0]=f2b(a.x);o[1]=f2b(a.y);o[2]=f2b(a.z);o[3]=f2b(a.w);
  o[4]=f2b(b.x);o[5]=f2b(b.y);o[6]=f2b(b.z);o[7]=f2b(b.w);
  ((uint4*)out)[i] = *(const uint4*)o;
}

// ---------------- column-mean partials: src [l][R][D] -> part[(l*S+s)*D + d] ---------------
__global__ void colsum_part_l(const float* __restrict__ src, float* __restrict__ part,
                              int R, int S){
  const int d = blockIdx.x*256 + threadIdx.x;
  const int s = blockIdx.y, l = blockIdx.z;
  const int rows = R / S;
  const float* p = src + (size_t)l*R*D_ + (size_t)s*rows*D_ + d;
  float acc = 0.f;
  for(int r=0;r<rows;++r) acc += p[(size_t)r*D_];
  part[((size_t)l*S + s)*D_ + d] = acc;
}

// MODE 0: mean (a*inv); 1: tanh(a+bias); 2: a+bias
template<int MODE>
__global__ void reduce_LD(const float* __restrict__ part, const float* __restrict__ bias,
                          float* __restrict__ out, int S, float inv){
  const int i = blockIdx.x*256 + threadIdx.x;
  const int l = i >> 12, j = i & (D_-1);
  float a = 0.f;
  for(int s=0;s<S;++s) a += part[((size_t)l*S + s)*D_ + j];
  if(MODE==0)      out[i] = a * inv;
  else if(MODE==1) out[i] = tanhf(a + bias[j]);
  else             out[i] = a + bias[j];
}

// ------------- small-M (24-row) GEMM partials over split-K ----------------
template<int WHICH>
__global__ void smallm_part(const float* __restrict__ W, const float* __restrict__ y,
                            const float* __restrict__ e, const float* __restrict__ tg,
                            float* __restrict__ part, int klen){
  const int j = blockIdx.x*256 + threadIdx.x;
  const int s = blockIdx.y, S = gridDim.y;
  const int k0 = s * klen;
  float acc[L_];
#pragma unroll
  for(int l=0;l<L_;++l) acc[l]=0.f;
  __shared__ float xs[L_][64];
  for(int kc=0; kc<klen; kc+=64){
    __syncthreads();
    for(int i=threadIdx.x; i<L_*64; i+=256){
      const int l=i>>6, kk=i&63, k=k0+kc+kk;
      float xv;
      if(WHICH==0) xv = (k<D_)? y[(size_t)l*D_+k] : e[(size_t)l*D_ + (k-D_)];
      else xv = (k<D_)? y[(size_t)l*D_+k]
              : ((k<2*D_)? e[(size_t)l*D_ + (k-D_)] : tg[k-2*D_]);
      xs[l][kk]=xv;
    }
    __syncthreads();
    for(int kk=0;kk<64;++kk){
      const int k=k0+kc+kk;
      const int wrow = (WHICH==0)? k : ((k<D_)? k : k+D_);
      const float wv = W[(size_t)wrow*D_ + j];
#pragma unroll
      for(int l=0;l<L_;++l) acc[l] += xs[l][kk]*wv;
    }
  }
  for(int l=0;l<L_;++l) part[((size_t)l*S + s)*D_ + j] = acc[l];
}

// ------------- recurrence: split-K matvec with bf16 Wz_c, then gate -------------
__global__ void matvec_part_b(const unsigned short* __restrict__ Wzc, const float* __restrict__ c,
                              float* __restrict__ zpart){
  const int j = blockIdx.x*256 + threadIdx.x;
  const int s = blockIdx.y;
  const int k0 = s*128;
  __shared__ float cs[128];
  if(threadIdx.x<128) cs[threadIdx.x] = c[k0+threadIdx.x];
  __syncthreads();
  float acc=0.f;
  const unsigned short* Wp = Wzc + (size_t)k0*D_ + j;
  for(int kk=0; kk<128; ++kk) acc += cs[kk]*b2f(Wp[(size_t)kk*D_]);
  zpart[(size_t)s*D_ + j]=acc;
}

__global__ void gate_step(const float* __restrict__ zpart, const float* __restrict__ aall,
                          const float* __restrict__ ct, float* __restrict__ c, int l){
  const int j = blockIdx.x*256+threadIdx.x;
  float zl = aall[(size_t)l*D_ + j];
  for(int s=0;s<32;++s) zl += zpart[(size_t)s*D_ + j];
  const float z = 1.f/(1.f + expf(-zl*(1.f/3.f)));
  const float cp = c[j];
  c[j] = cp + z*(ct[(size_t)l*D_ + j] - cp);
}

__global__ void zero_vec(float* p){ p[blockIdx.x*256+threadIdx.x]=0.f; }

// ---------------- row LayerNorm (D=4096), 256 thr/row ----------------
template<bool ADDC, bool AFF, bool OBF>
__global__ void row_ln(const float* __restrict__ x, const float* __restrict__ cvec,
                       const float* __restrict__ w, const float* __restrict__ b,
                       float* __restrict__ of, unsigned short* __restrict__ ob){
  __shared__ float sm[256];
  const int row = blockIdx.x, t = threadIdx.x;
  const float* xr = x + (size_t)row*D_;
  float v[16];
  float s=0.f;
#pragma unroll
  for(int i=0;i<16;++i){
    const int d = i*256 + t;
    float val = xr[d];
    if(ADDC) val += cvec[d];
    v[i]=val; s+=val;
  }
  sm[t]=s; __syncthreads();
  for(int o=128;o>0;o>>=1){ if(t<o) sm[t]+=sm[t+o]; __syncthreads(); }
  const float mean = sm[0]*(1.f/D_); __syncthreads();
  float q=0.f;
#pragma unroll
  for(int i=0;i<16;++i){ const float dd=v[i]-mean; q+=dd*dd; }
  sm[t]=q; __syncthreads();
  for(int o=128;o>0;o>>=1){ if(t<o) sm[t]+=sm[t+o]; __syncthreads(); }
  const float rstd = rsqrtf(sm[0]*(1.f/D_) + 1e-5f);
#pragma unroll
  for(int i=0;i<16;++i){
    const int d = i*256+t;
    float yv=(v[i]-mean)*rstd;
    if(AFF) yv = yv*w[d] + b[d];
    if(OBF) ob[(size_t)row*D_ + d] = f2b(yv);
    else    of[(size_t)row*D_ + d] = yv;
  }
}

// ---------------- row softmax in-place on bf16 [rows][N_] ----------------
__global__ void softmax_rows(unsigned short* __restrict__ wb){
  __shared__ float sm[256];
  const size_t base = (size_t)blockIdx.x * N_;
  const int t = threadIdx.x;
  float v[8];
  float mx = -3.4e38f;
#pragma unroll
  for(int i=0;i<8;++i){ v[i]=b2f(wb[base + i*256 + t]); mx=fmaxf(mx,v[i]); }
  sm[t]=mx; __syncthreads();
  for(int o=128;o>0;o>>=1){ if(t<o) sm[t]=fmaxf(sm[t],sm[t+o]); __syncthreads(); }
  mx=sm[0]; __syncthreads();
  float s=0.f;
#pragma unroll
  for(int i=0;i<8;++i){ v[i]=expf(v[i]-mx); s+=v[i]; }
  sm[t]=s; __syncthreads();
  for(int o=128;o>0;o>>=1){ if(t<o) sm[t]+=sm[t+o]; __syncthreads(); }
  const float inv = 1.f/sm[0];
#pragma unroll
  for(int i=0;i<8;++i) wb[base + i*256 + t] = f2b(v[i]*inv);
}

enum { EPI_F32_BIAS=0, EPI_BF16_GELU=1, EPI_SPATIAL=2, EPI_BF16_SCALE=3, EPI_BF16=4 };

// ---------------- m97-structure GEMM: bf16 A [M][K] x bf16 BT [N][K], gload_lds ----------------
constexpr int GBM=128, GBN=128, GBK=32;

template<int EPI>
__global__ __launch_bounds__(256,2) void gemm_bt(
  const unsigned short* __restrict__ A, const unsigned short* __restrict__ BT,
  const float* __restrict__ bias,
  float* __restrict__ Cf, unsigned short* __restrict__ Cb,
  int M, int Ncols, int K, int lda, int ldb, int ldc,
  long long aZ, long long bZ, long long cZ,
  const float* __restrict__ pre, const float* __restrict__ alphap, float scale)
{
  __shared__ unsigned short As[GBM*GBK];
  __shared__ unsigned short Bs[GBN*GBK];
  const int t = threadIdx.x;
  const int lane = t&63, wid = t>>6;
  const int m0 = blockIdx.x*GBM, n0 = blockIdx.y*GBN;
  A  += (size_t)blockIdx.z*aZ;
  BT += (size_t)blockIdx.z*bZ;
  const size_t coff = (size_t)blockIdx.z*cZ;

  // staging: lane handles row = c*64 + wid*16 + (lane>>2), 8 elems at col (lane&3)*8
  const int srow = wid*16 + (lane>>2);
  const int scol = (lane&3)*8;
  const unsigned short* ag = A  + (size_t)(m0+srow)*lda + scol;
  const unsigned short* bg = BT + (size_t)(n0+srow)*ldb + scol;
  unsigned short* asl = &As[wid*512];
  unsigned short* bsl = &Bs[wid*512];

  f32x4 acc[4][4];
#pragma unroll
  for(int i=0;i<4;++i)
#pragma unroll
    for(int j=0;j<4;++j) acc[i][j]=(f32x4){0.f,0.f,0.f,0.f};

  const int wm=(wid>>1)*64, wn=(wid&1)*64;
  const int lrow=lane&15, lk=(lane>>4)*8;

  for(int k0=0;k0<K;k0+=GBK){
    __syncthreads();
    gload_lds16(ag + k0,                    asl);
    gload_lds16(ag + k0 + (size_t)64*lda,   asl + 2048);
    gload_lds16(bg + k0,                    bsl);
    gload_lds16(bg + k0 + (size_t)64*ldb,   bsl + 2048);
    __syncthreads();
    short8 af[4], bfr[4];
#pragma unroll
    for(int i=0;i<4;++i) af[i]  = *(const short8*)&As[(wm+i*16+lrow)*GBK + lk];
#pragma unroll
    for(int j=0;j<4;++j) bfr[j] = *(const short8*)&Bs[(wn+j*16+lrow)*GBK + lk];
#pragma unroll
    for(int i=0;i<4;++i)
#pragma unroll
      for(int j=0;j<4;++j)
        acc[i][j] = __builtin_amdgcn_mfma_f32_16x16x32_bf16(af[i], bfr[j], acc[i][j], 0,0,0);
  }

  float ta=0.f;
  if(EPI==EPI_SPATIAL) ta = tanhf(alphap[0]);
#pragma unroll
  for(int i=0;i<4;++i)
#pragma unroll
    for(int j=0;j<4;++j){
      const int col = n0 + wn + j*16 + lrow;
      const int rb  = m0 + wm + i*16 + (lane>>4)*4;
#pragma unroll
      for(int r=0;r<4;++r){
        const int row = rb + r;
        const float v = acc[i][j][r];
        const size_t idx = coff + (size_t)row*ldc + col;
        if(EPI==EPI_F32_BIAS){ Cf[idx] = v + bias[col]; }
        else if(EPI==EPI_BF16_GELU){
          const float x=v+bias[col];
          Cb[idx]=f2b(0.5f*x*(1.f+erff(x*0.70710678118f)));
        }
        else if(EPI==EPI_SPATIAL){
          const float x=tanhf(v+bias[col]);
          const float o= pre[(size_t)row*ldc+col] + ta*x;
          Cf[idx]=o; Cb[idx]=f2b(o);
        }
        else if(EPI==EPI_BF16_SCALE){ Cb[idx]=f2b(v*scale); }
        else { Cb[idx]=f2b(v); }
      }
    }
}

// ---------------- register-staged GEMM kept for PV (B=[K][N] bf16) ----------------
constexpr int BM=128, BN=128, BK=32, LDT=56;

__device__ __forceinline__ void ld2f(const unsigned short* p, float& a, float& b){
  unsigned v=*(const unsigned*)p; a=b2f((unsigned short)(v&0xffffu)); b=b2f((unsigned short)(v>>16));
}

__global__ __launch_bounds__(256,2) void gemm_pv(
  const unsigned short* __restrict__ A, const unsigned short* __restrict__ B,
  unsigned short* __restrict__ Cb,
  int M, int Ncols, int K, int lda, int ldb, int ldc,
  long long aZ, long long bZ, long long cZ)
{
  __shared__ unsigned short As[BM*LDT];
  __shared__ unsigned short Bs[BN*LDT];
  const int t = threadIdx.x;
  const int m0 = blockIdx.x*BM, n0 = blockIdx.y*BN;
  A += (size_t)blockIdx.z*aZ; B += (size_t)blockIdx.z*bZ;
  const size_t coff = (size_t)blockIdx.z*cZ;

  f32x4 acc[4][4];
#pragma unroll
  for(int i=0;i<4;++i)
#pragma unroll
    for(int j=0;j<4;++j) acc[i][j]=(f32x4){0.f,0.f,0.f,0.f};

  const int lane = t&63, wid=t>>6;
  const int wm=(wid>>1)*64, wn=(wid&1)*64;
  const int lrow=lane&15, lk=(lane>>4)*8;

  for(int k0=0;k0<K;k0+=BK){
    __syncthreads();
    { // A stage
      const int row=t>>1, kq=(t&1)*16;
      const unsigned short* ap = A + (size_t)(m0+row)*lda + k0 + kq;
      *(uint4*)&As[row*LDT+kq]   = *(const uint4*)ap;
      *(uint4*)&As[row*LDT+kq+8] = *(const uint4*)(ap+8);
    }
    { // B [K][N] transpose staging
      const int ln_=t&63, grp=t>>6;
      const unsigned short* bp = B + (size_t)(k0+grp*8)*ldb + n0 + 2*ln_;
      unsigned short c0[8] __attribute__((aligned(16)));
      unsigned short c1[8] __attribute__((aligned(16)));
#pragma unroll
      for(int q=0;q<8;++q){
        float x0,x1; ld2f(bp + (size_t)q*ldb, x0,x1);
        c0[q]=f2b(x0); c1[q]=f2b(x1);
      }
      *(uint4*)&Bs[(2*ln_+0)*LDT + grp*8] = *(const uint4*)&c0[0];
      *(uint4*)&Bs[(2*ln_+1)*LDT + grp*8] = *(const uint4*)&c1[0];
    }
    __syncthreads();
    short8 af[4], bfr[4];
#pragma unroll
    for(int i=0;i<4;++i) af[i]  = *(const short8*)&As[(wm+i*16+lrow)*LDT + lk];
#pragma unroll
    for(int j=0;j<4;++j) bfr[j] = *(const short8*)&Bs[(wn+j*16+lrow)*LDT + lk];
#pragma unroll
    for(int i=0;i<4;++i)
#pragma unroll
      for(int j=0;j<4;++j)
        acc[i][j] = __builtin_amdgcn_mfma_f32_16x16x32_bf16(af[i], bfr[j], acc[i][j], 0,0,0);
  }

#pragma unroll
  for(int i=0;i<4;++i)
#pragma unroll
    for(int j=0;j<4;++j){
      const int col = n0 + wn + j*16 + lrow;
      const int rb  = m0 + wm + i*16 + (lane>>4)*4;
#pragma unroll
      for(int r=0;r<4;++r)
        Cb[coff + (size_t)(rb+r)*ldc + col] = f2b(acc[i][j][r]);
    }
}

// ---------------- workspace layout (bytes) ----------------
constexpr size_t OFF_TG   = 0;
constexpr size_t OFF_GM   = OFF_TG + (size_t)D_*4;
constexpr size_t OFF_C    = OFF_GM + (size_t)D_*4;
constexpr size_t OFF_Y    = OFF_C  + (size_t)D_*4;
constexpr size_t OFF_CT   = OFF_Y  + (size_t)L_*D_*4;
constexpr size_t OFF_AA   = OFF_CT + (size_t)L_*D_*4;
constexpr size_t OFF_ZP   = OFF_AA + (size_t)L_*D_*4;
constexpr size_t OFF_PART = OFF_ZP + (size_t)32*D_*4;
constexpr size_t OFF_QPRE = OFF_PART + (size_t)24*L_*D_*4;   // also opre
constexpr size_t OFF_REFR = OFF_QPRE + (size_t)T_*D_*4;
constexpr size_t OFF_HB   = OFF_REFR + (size_t)N_*D_*4;      // bf16; kpre (fp32) reuses HB+G1
constexpr size_t OFF_G1   = OFF_HB + (size_t)N_*D_*2;
constexpr size_t OFF_KPRE = OFF_HB;
constexpr size_t OFF_QB   = OFF_G1 + (size_t)N_*D_*2;
constexpr size_t OFF_KB   = OFF_QB + (size_t)T_*D_*2;
constexpr size_t OFF_VB   = OFF_KB + (size_t)N_*D_*2;
constexpr size_t OFF_WB   = OFF_VB + (size_t)N_*D_*2;        // scores/weights bf16 [H][T][N]
constexpr size_t OFF_ATTN = OFF_WB + (size_t)H_*T_*N_*2;
constexpr size_t OFF_W1T  = OFF_ATTN + (size_t)T_*D_*2;      // bf16 transposed weights
constexpr size_t OFF_W2T  = OFF_W1T + (size_t)D_*D_*2;
constexpr size_t OFF_WKT  = OFF_W2T + (size_t)D_*D_*2;
constexpr size_t OFF_WQT  = OFF_WKT + (size_t)D_*D_*2;
constexpr size_t OFF_WOT  = OFF_WQT + (size_t)D_*D_*2;
constexpr size_t OFF_WZCB = OFF_WOT + (size_t)D_*D_*2;       // bf16 Wz rows D..2D
constexpr size_t OFF_TXB  = OFF_WZCB + (size_t)D_*D_*2;      // bf16 text
constexpr size_t OFF_REFB = OFF_TXB + (size_t)T_*D_*2;       // bf16 refreshed

extern "C" void kernel_launch(void* const* d_in, const int* in_sizes, int n_in,
                              void* d_out, int out_size, void* d_ws, size_t ws_size,
                              hipStream_t stream){
  (void)in_sizes; (void)n_in; (void)out_size; (void)ws_size;
  const float* text  = (const float*)d_in[0];
  const float* layers= (const float*)d_in[1];
  const float* le    = (const float*)d_in[2];
  const float* Wc    = (const float*)d_in[3];
  const float* Wcb   = (const float*)d_in[4];
  const float* Wz    = (const float*)d_in[5];
  const float* Wzb   = (const float*)d_in[6];
  const float* d1w   = (const float*)d_in[7];
  const float* d1b   = (const float*)d_in[8];
  const float* d2w   = (const float*)d_in[9];
  const float* d2b   = (const float*)d_in[10];
  const float* alpha = (const float*)d_in[11];
  const float* Wqw=(const float*)d_in[12]; const float* Wqb=(const float*)d_in[13];
  const float* Wkw=(const float*)d_in[14]; const float* Wkb=(const float*)d_in[15];
  const float* Wow=(const float*)d_in[16]; const float* Wob=(const float*)d_in[17];
  const float* qnw=(const float*)d_in[18]; const float* qnb=(const float*)d_in[19];
  const float* knw=(const float*)d_in[20]; const float* knb=(const float*)d_in[21];
  const float* vnw=(const float*)d_in[22]; const float* vnb=(const float*)d_in[23];
  const float* onw=(const float*)d_in[24]; const float* onb=(const float*)d_in[25];
  float* out = (float*)d_out;

  char* w = (char*)d_ws;
  float* tg    = (float*)(w + OFF_TG);
  float* gm    = (float*)(w + OFF_GM);
  float* cvec  = (float*)(w + OFF_C);
  float* y     = (float*)(w + OFF_Y);
  float* ct    = (float*)(w + OFF_CT);
  float* aall  = (float*)(w + OFF_AA);
  float* zpart = (float*)(w + OFF_ZP);
  float* part  = (float*)(w + OFF_PART);
  float* qpre  = (float*)(w + OFF_QPRE);
  float* opre  = qpre;
  float* refr  = (float*)(w + OFF_REFR);
  float* kpre  = (float*)(w + OFF_KPRE);
  unsigned short* hb    = (unsigned short*)(w + OFF_HB);
  unsigned short* g1    = (unsigned short*)(w + OFF_G1);
  unsigned short* qb    = (unsigned short*)(w + OFF_QB);
  unsigned short* kb    = (unsigned short*)(w + OFF_KB);
  unsigned short* vb    = (unsigned short*)(w + OFF_VB);
  unsigned short* wb    = (unsigned short*)(w + OFF_WB);
  unsigned short* attnb = (unsigned short*)(w + OFF_ATTN);
  unsigned short* d1t   = (unsigned short*)(w + OFF_W1T);
  unsigned short* d2t   = (unsigned short*)(w + OFF_W2T);
  unsigned short* wkt   = (unsigned short*)(w + OFF_WKT);
  unsigned short* wqt   = (unsigned short*)(w + OFF_WQT);
  unsigned short* wot   = (unsigned short*)(w + OFF_WOT);
  unsigned short* wzcb  = (unsigned short*)(w + OFF_WZCB);
  unsigned short* txb   = (unsigned short*)(w + OFF_TXB);
  unsigned short* refb  = (unsigned short*)(w + OFF_REFB);

  const dim3 b256(256);
  const dim3 tgrid(64,64);
  const float* pre23 = layers + (size_t)(L_-2)*N_*D_;

  // ---- prepass: weight transposes/conversions (independent of everything else)
  transpose_f32_bf16T<<<tgrid,b256,0,stream>>>(d1w, d1t, D_, D_);
  transpose_f32_bf16T<<<tgrid,b256,0,stream>>>(d2w, d2t, D_, D_);
  transpose_f32_bf16T<<<tgrid,b256,0,stream>>>(Wkw, wkt, D_, D_);
  transpose_f32_bf16T<<<tgrid,b256,0,stream>>>(Wqw, wqt, D_, D_);
  transpose_f32_bf16T<<<tgrid,b256,0,stream>>>(Wow, wot, D_, D_);
  cvt_f32_bf16<<<dim3(D_*D_/8/256),b256,0,stream>>>(Wz + (size_t)D_*D_, wzcb);
  cvt_f32_bf16<<<dim3(T_*D_/8/256),b256,0,stream>>>(text, txb);

  // text_global = LN(mean(text, axis=0))
  colsum_part_l<<<dim3(16,8,1),b256,0,stream>>>(text, part, T_, 8);
  reduce_LD<0><<<dim3(16),b256,0,stream>>>(part, nullptr, gm, 8, 1.f/T_);
  row_ln<false,false,false><<<dim3(1),b256,0,stream>>>(gm, nullptr,nullptr,nullptr, tg, nullptr);

  // y[l] = mean(layer_features[l], axis=0)
  colsum_part_l<<<dim3(16,8,24),b256,0,stream>>>(layers, part, N_, 8);
  reduce_LD<0><<<dim3(384),b256,0,stream>>>(part, nullptr, y, 8, 1.f/N_);

  // c_tilde batch and z-logit static part
  smallm_part<0><<<dim3(16,16),b256,0,stream>>>(Wc, y, le, tg, part, 512);
  reduce_LD<1><<<dim3(384),b256,0,stream>>>(part, Wcb, ct, 16, 0.f);
  smallm_part<1><<<dim3(16,24),b256,0,stream>>>(Wz, y, le, tg, part, 512);
  reduce_LD<2><<<dim3(384),b256,0,stream>>>(part, Wzb, aall, 24, 0.f);

  // recurrence, steps 0..22 -> c = contexts[-2]
  zero_vec<<<dim3(16),b256,0,stream>>>(cvec);
  for(int l=0;l<L_-1;++l){
    matvec_part_b<<<dim3(16,32),b256,0,stream>>>(wzcb, cvec, zpart);
    gate_step<<<dim3(16),b256,0,stream>>>(zpart, aall, ct, cvec, l);
  }

  // SpatialGate
  row_ln<true,false,true><<<dim3(N_),b256,0,stream>>>(pre23, cvec, nullptr,nullptr, nullptr, hb);
  gemm_bt<EPI_BF16_GELU><<<dim3(16,32,1),b256,0,stream>>>(
      hb, d1t, d1b, nullptr, g1, N_, D_, D_, D_, D_, D_, 0,0,0, nullptr,nullptr,0.f);
  gemm_bt<EPI_SPATIAL><<<dim3(16,32,1),b256,0,stream>>>(
      g1, d2t, d2b, refr, refb, N_, D_, D_, D_, D_, D_, 0,0,0, pre23, alpha, 0.f);

  // Q / K / V
  gemm_bt<EPI_F32_BIAS><<<dim3(4,32,1),b256,0,stream>>>(
      txb, wqt, Wqb, qpre, nullptr, T_, D_, D_, D_, D_, D_, 0,0,0, nullptr,nullptr,0.f);
  row_ln<false,true,true><<<dim3(T_),b256,0,stream>>>(qpre, nullptr, qnw, qnb, nullptr, qb);
  row_ln<false,true,true><<<dim3(N_),b256,0,stream>>>(refr, nullptr, vnw, vnb, nullptr, vb);
  gemm_bt<EPI_F32_BIAS><<<dim3(16,32,1),b256,0,stream>>>(
      refb, wkt, Wkb, kpre, nullptr, N_, D_, D_, D_, D_, D_, 0,0,0, nullptr,nullptr,0.f);
  row_ln<false,true,true><<<dim3(N_),b256,0,stream>>>(kpre, nullptr, knw, knb, nullptr, kb);

  // attention: scores = Q Kt (per head), softmax, PV
  gemm_bt<EPI_BF16_SCALE><<<dim3(4,16,8),b256,0,stream>>>(
      qb, kb, nullptr, nullptr, wb, T_, N_, HD_, D_, D_, N_,
      (long long)HD_, (long long)HD_, (long long)T_*N_, nullptr,nullptr, SCALE_);
  softmax_rows<<<dim3(H_*T_),b256,0,stream>>>(wb);
  gemm_pv<<<dim3(4,4,8),b256,0,stream>>>(
      wb, vb, attnb, T_, HD_, N_, N_, D_, D_,
      (long long)T_*N_, (long long)HD_, (long long)HD_);

  // output projection + final LN
  gemm_bt<EPI_F32_BIAS><<<dim3(4,32,1),b256,0,stream>>>(
      attnb, wot, Wob, opre, nullptr, T_, D_, D_, D_, D_, D_, 0,0,0, nullptr,nullptr,0.f);
  row_ln<false,true,false><<<dim3(T_),b256,0,stream>>>(opre, nullptr, onw, onb, out, nullptr);
}